// Round 7
// baseline (229.912 us; speedup 1.0000x reference)
//
#include <hip/hip_runtime.h>

// Problem constants (from reference setup_inputs)
constexpr int B = 16;
constexpr int D = 256;
constexpr int K = 18;
constexpr int SZ = 128;
constexpr int S = SZ * SZ;      // 16384 positions per plane
constexpr int N = S / 2;        // 8192 sampled positions
constexpr int PB = 512;         // positions per block (fused kernel)

// ---------------------------------------------------------------------------
// Prep: blocks 0..31 scatter mask ones (mask pre-zeroed by memset);
// blocks 32..103 compute p2[b*K+k] = ||proto||^2 fp64 (one row per warp);
// blocks 104..391 transpose proto -> p64[b][d][k] (fp64, dot phase) and
// pT32[b][d][k] (fp32, output phase: 18 contiguous floats per (b,d)).
// ---------------------------------------------------------------------------
__global__ __launch_bounds__(256) void prep_kernel(
    const float* __restrict__ proto,
    const int* __restrict__ idx,
    unsigned char* __restrict__ mask,
    double* __restrict__ p2,
    double* __restrict__ p64,
    float* __restrict__ pT32) {
  const int blk = blockIdx.x;
  if (blk < 32) {
    mask[idx[blk * 256 + threadIdx.x]] = 1;   // indices are a permutation
  } else if (blk < 104) {
    const int row  = (blk - 32) * 4 + (threadIdx.x >> 6);  // 0..287 = b*K+k
    const int lane = threadIdx.x & 63;
    const float4 v = *(const float4*)(proto + (size_t)row * D + lane * 4);
    double s = (double)v.x * (double)v.x + (double)v.y * (double)v.y
             + (double)v.z * (double)v.z + (double)v.w * (double)v.w;
#pragma unroll
    for (int off = 1; off < 64; off <<= 1)
      s += __shfl_xor(s, off, 64);
    if (lane == 0) p2[row] = s;
  } else {
    const int e = (blk - 104) * 256 + threadIdx.x;   // 0..B*D*K-1 exactly
    const int b = e / (D * K);
    const int r = e - b * (D * K);
    const int d = r / K;
    const int k = r - d * K;
    const float v = proto[((size_t)b * K + k) * D + d];
    p64[e]  = (double)v;
    pT32[e] = v;
  }
}

// ---------------------------------------------------------------------------
// Fused argmin + output. Block = 128 threads (2 waves), (b, 512-pos chunk).
// Each thread owns 4 positions: pos0 + 2*tid + {0,1} and + 256 + {0,1}.
//  dot:    f via coalesced float2 global loads (vmcnt), protos via fp64 LDS
//          broadcast ds_read (lgkmcnt) -- independent counters, so the
//          round-6 s_load/lgkmcnt interlock is gone. 18 DS reads per d per
//          wave feed 72 FMAs (P=4 amortization; round 5 was 36).
//  argmin: per-thread over ascending k, strict < = numpy first-min.
//          fp64 acc, d-order 0..255 per position -> decisions identical to
//          rounds 1-5 (absmax 0.0 each time).
//  output: re-read f (L3-hot), select vs pT32[b][d][kst] (2 L1 lines/wave),
//          coalesced float2 stores. Input read once from HBM, output written
//          exactly once.
// ---------------------------------------------------------------------------
__global__ __launch_bounds__(128, 2) void fused_kernel(
    const float* __restrict__ assp,
    const double* __restrict__ p64,
    const float* __restrict__ pT32,
    const double* __restrict__ p2,
    const unsigned char* __restrict__ mask,
    float* __restrict__ out) {
  __shared__ double spd[D * K];   // 36 KiB -> 4 blocks/CU, 8 waves/CU

  const int b     = blockIdx.x & 15;    // batches spread across XCDs
  const int chunk = blockIdx.x >> 4;    // 0..31
  const int pos0  = chunk * PB;
  const int tid   = threadIdx.x;        // 0..127

  const double* pb = p64 + (size_t)b * D * K;
  for (int i = tid; i < D * K; i += 128) spd[i] = pb[i];
  __syncthreads();

  const float* fin = assp + (size_t)(b * D) * S + pos0 + 2 * tid;

  double acc[4][K];   // [pos-slot][k]; slots: {0,1} = +0,+1; {2,3} = +256,+257
#pragma unroll
  for (int jp = 0; jp < 4; ++jp)
#pragma unroll
    for (int k = 0; k < K; ++k) acc[jp][k] = 0.0;

  for (int d0 = 0; d0 < D; d0 += 8) {
    float2 fv[8][2];
#pragma unroll
    for (int jd = 0; jd < 8; ++jd) {
      fv[jd][0] = *(const float2*)(fin + (size_t)(d0 + jd) * S);
      fv[jd][1] = *(const float2*)(fin + (size_t)(d0 + jd) * S + 256);
    }
#pragma unroll
    for (int jd = 0; jd < 8; ++jd) {
      const double f0 = (double)fv[jd][0].x;
      const double f1 = (double)fv[jd][0].y;
      const double f2 = (double)fv[jd][1].x;
      const double f3 = (double)fv[jd][1].y;
      const double* pr = &spd[(d0 + jd) * K];
#pragma unroll
      for (int k = 0; k < K; ++k) {
        const double pk = pr[k];    // wave-uniform -> LDS broadcast
        acc[0][k] += f0 * pk;
        acc[1][k] += f1 * pk;
        acc[2][k] += f2 * pk;
        acc[3][k] += f3 * pk;
      }
    }
  }

  // ---- per-position argmin (strict <, ascending k = numpy first-min) ----
  const double* p2b = p2 + b * K;
  double best[4];
  int kst[4];
#pragma unroll
  for (int jp = 0; jp < 4; ++jp) { best[jp] = 1e300; kst[jp] = 0; }
#pragma unroll
  for (int k = 0; k < K; ++k) {
    const double pk2 = p2b[k];
#pragma unroll
    for (int jp = 0; jp < 4; ++jp) {
      const double d2 = pk2 - 2.0 * acc[jp][k];
      if (d2 < best[jp]) { best[jp] = d2; kst[jp] = k; }
    }
  }

  // ---- output: out = mask ? proto[kst][d] : f ----
  const uchar2 m0 = *(const uchar2*)(mask + pos0 + 2 * tid);
  const uchar2 m1 = *(const uchar2*)(mask + pos0 + 256 + 2 * tid);
  const float* pt = pT32 + (size_t)b * D * K;
  float* op = out + (size_t)(b * D) * S + pos0 + 2 * tid;

  for (int d0 = 0; d0 < D; d0 += 8) {
#pragma unroll
    for (int jd = 0; jd < 8; ++jd) {
      const int d = d0 + jd;
      const float2 fa = *(const float2*)(fin + (size_t)d * S);
      const float2 fb = *(const float2*)(fin + (size_t)d * S + 256);
      const float* prow = pt + d * K;   // 18 contiguous floats, L1-hot
      float2 oa, ob;
      oa.x = m0.x ? prow[kst[0]] : fa.x;
      oa.y = m0.y ? prow[kst[1]] : fa.y;
      ob.x = m1.x ? prow[kst[2]] : fb.x;
      ob.y = m1.y ? prow[kst[3]] : fb.y;
      *(float2*)(op + (size_t)d * S) = oa;
      *(float2*)(op + (size_t)d * S + 256) = ob;
    }
  }
}

extern "C" void kernel_launch(void* const* d_in, const int* in_sizes, int n_in,
                              void* d_out, int out_size, void* d_ws, size_t ws_size,
                              hipStream_t stream) {
  const float* assp  = (const float*)d_in[0];
  const float* proto = (const float*)d_in[1];
  const int*   idx   = (const int*)d_in[2];
  float* out = (float*)d_out;

  // ws layout: [mask: S][p2: B*K dbl][p64: B*D*K dbl][pT32: B*D*K f32]
  unsigned char* mask = (unsigned char*)d_ws;
  double*        p2   = (double*)((char*)d_ws + S);
  double*        p64  = (double*)((char*)d_ws + S + (size_t)B * K * 8);
  float*         pT32 = (float*)((char*)p64 + (size_t)B * D * K * 8);

  hipMemsetAsync(mask, 0, S, stream);   // 16 KiB
  prep_kernel<<<392, 256, 0, stream>>>(proto, idx, mask, p2, p64, pT32);
  fused_kernel<<<B * (S / PB), 128, 0, stream>>>(assp, p64, pT32, p2, mask, out);
}

// Round 8
// 208.862 us; speedup vs baseline: 1.1008x; 1.1008x over previous
//
#include <hip/hip_runtime.h>

// Problem constants (from reference setup_inputs)
constexpr int B = 16;
constexpr int D = 256;
constexpr int K = 18;
constexpr int SZ = 128;
constexpr int S = SZ * SZ;      // 16384 positions per plane
constexpr int N = S / 2;        // 8192 sampled positions
constexpr int PSTR = 24;        // fp64 proto row stride (192 B, 64B-aligned)
constexpr int PB = 512;         // positions per block (fused kernel)

// ---------------------------------------------------------------------------
// Prep: blocks 0..31 scatter mask ones (mask pre-zeroed by memset);
// blocks 32..103 compute p2[b*K+k] = ||proto||^2 fp64 (one row per warp);
// blocks 104..391 transpose proto -> p64[b][d][0..17] fp64 (row stride 24 for
// 64B-aligned rows -> wide s_load in the fused dot) and pT32[b][d][k] fp32
// (output-phase gather, 18 KB per batch -> L1-resident).
// ---------------------------------------------------------------------------
__global__ __launch_bounds__(256) void prep_kernel(
    const float* __restrict__ proto,
    const int* __restrict__ idx,
    unsigned char* __restrict__ mask,
    double* __restrict__ p2,
    double* __restrict__ p64,
    float* __restrict__ pT32) {
  const int blk = blockIdx.x;
  if (blk < 32) {
    mask[idx[blk * 256 + threadIdx.x]] = 1;   // indices are a permutation
  } else if (blk < 104) {
    const int row  = (blk - 32) * 4 + (threadIdx.x >> 6);  // 0..287 = b*K+k
    const int lane = threadIdx.x & 63;
    const float4 v = *(const float4*)(proto + (size_t)row * D + lane * 4);
    double s = (double)v.x * (double)v.x + (double)v.y * (double)v.y
             + (double)v.z * (double)v.z + (double)v.w * (double)v.w;
#pragma unroll
    for (int off = 1; off < 64; off <<= 1)
      s += __shfl_xor(s, off, 64);
    if (lane == 0) p2[row] = s;
  } else {
    const int e = (blk - 104) * 256 + threadIdx.x;   // 0..B*D*K-1 exactly
    const int b = e / (D * K);
    const int r = e - b * (D * K);
    const int d = r / K;
    const int k = r - d * K;
    const float v = proto[((size_t)b * K + k) * D + d];
    p64[((size_t)b * D + d) * PSTR + k] = (double)v;
    pT32[((size_t)b * D + d) * K + k]   = v;
  }
}

// ---------------------------------------------------------------------------
// Fused argmin + output. Block = 256 threads (4 waves), (b, 512-pos chunk).
// Each thread owns the adjacent position pair pos0 + 2*tid + {0,1}.
//  dot:    f via coalesced float2 global loads (vmcnt); protos via
//          WAVE-UNIFORM s_load from p64 (lgkmcnt, SMEM only -- no DS
//          anywhere, so no ds/smem lgkmcnt interlock and zero LDS-pipe
//          cost; fp64 FMA takes the SGPR pair as one scalar operand).
//  argmin: strict < over ascending k = numpy first-min. fp64 acc, d-order
//          0..255 per position -> decisions identical to rounds 1-5.
//  output: walk d DESCENDING so the f re-read hits the L2/L3 tail the dot
//          phase just left; select vs pT32[d][kst] (L1-hot gather);
//          coalesced float2 stores, output written exactly once.
// ---------------------------------------------------------------------------
__global__ __launch_bounds__(256, 2) void fused_kernel(
    const float* __restrict__ assp,
    const double* __restrict__ p64,
    const float* __restrict__ pT32,
    const double* __restrict__ p2,
    const unsigned char* __restrict__ mask,
    float* __restrict__ out) {
  const int b     = blockIdx.x & 15;    // batches spread across XCDs
  const int chunk = blockIdx.x >> 4;    // 0..31
  const int pos0  = chunk * PB;
  const int tid   = threadIdx.x;        // 0..255

  const float*  fin = assp + (size_t)(b * D) * S + pos0 + 2 * tid;
  const double* pb  = p64 + (size_t)b * D * PSTR;   // uniform base

  double acc0[K], acc1[K];
#pragma unroll
  for (int k = 0; k < K; ++k) { acc0[k] = 0.0; acc1[k] = 0.0; }

  for (int d0 = 0; d0 < D; d0 += 8) {
    float2 fv[8];
#pragma unroll
    for (int jd = 0; jd < 8; ++jd)
      fv[jd] = *(const float2*)(fin + (size_t)(d0 + jd) * S);  // 8 loads in flight
#pragma unroll
    for (int jd = 0; jd < 8; ++jd) {
      const double f0 = (double)fv[jd].x;
      const double f1 = (double)fv[jd].y;
      const double* pr = pb + (size_t)(d0 + jd) * PSTR;  // uniform -> s_load
#pragma unroll
      for (int k = 0; k < K; ++k) {
        const double pk = pr[k];     // SGPR operand of v_fma_f64
        acc0[k] += f0 * pk;
        acc1[k] += f1 * pk;
      }
    }
  }

  // ---- per-position argmin (strict <, ascending k = numpy first-min) ----
  const double* p2b = p2 + b * K;      // uniform -> s_load
  double best0 = 1e300, best1 = 1e300;
  int kst0 = 0, kst1 = 0;
#pragma unroll
  for (int k = 0; k < K; ++k) {
    const double pk2 = p2b[k];
    const double d20 = pk2 - 2.0 * acc0[k];
    const double d21 = pk2 - 2.0 * acc1[k];
    if (d20 < best0) { best0 = d20; kst0 = k; }
    if (d21 < best1) { best1 = d21; kst1 = k; }
  }

  // ---- output: out = mask ? proto[kst][d] : f, d descending (L3 tail) ----
  const uchar2 m = *(const uchar2*)(mask + pos0 + 2 * tid);
  const float* g0 = pT32 + (size_t)b * D * K + kst0;   // per-lane gather bases
  const float* g1 = pT32 + (size_t)b * D * K + kst1;
  float* op = out + (size_t)(b * D) * S + pos0 + 2 * tid;

  for (int d0 = D - 8; d0 >= 0; d0 -= 8) {
    float2 fa[8];
    float  pa[8], pbv[8];
#pragma unroll
    for (int jd = 0; jd < 8; ++jd) {                  // all loads issued first
      const int d = d0 + jd;
      fa[jd]  = *(const float2*)(fin + (size_t)d * S);
      pa[jd]  = g0[(size_t)d * K];                    // L1-hot (18 KB table)
      pbv[jd] = g1[(size_t)d * K];
    }
#pragma unroll
    for (int jd = 0; jd < 8; ++jd) {
      const int d = d0 + jd;
      float2 o;
      o.x = m.x ? pa[jd]  : fa[jd].x;
      o.y = m.y ? pbv[jd] : fa[jd].y;
      *(float2*)(op + (size_t)d * S) = o;
    }
  }
}

extern "C" void kernel_launch(void* const* d_in, const int* in_sizes, int n_in,
                              void* d_out, int out_size, void* d_ws, size_t ws_size,
                              hipStream_t stream) {
  const float* assp  = (const float*)d_in[0];
  const float* proto = (const float*)d_in[1];
  const int*   idx   = (const int*)d_in[2];
  float* out = (float*)d_out;

  // ws layout: [p64: B*D*24 dbl][pT32: B*D*K f32][p2: B*K dbl][mask: S bytes]
  double*        p64  = (double*)d_ws;                               // 786432 B
  float*         pT32 = (float*)((char*)d_ws + (size_t)B * D * PSTR * 8);  // +294912
  double*        p2   = (double*)((char*)pT32 + (size_t)B * D * K * 4);    // +2304
  unsigned char* mask = (unsigned char*)((char*)p2 + (size_t)B * K * 8);   // +16384

  hipMemsetAsync(mask, 0, S, stream);   // 16 KiB
  prep_kernel<<<392, 256, 0, stream>>>(proto, idx, mask, p2, p64, pT32);
  fused_kernel<<<B * (S / PB), 256, 0, stream>>>(assp, p64, pT32, p2, mask, out);
}

// Round 9
// 190.624 us; speedup vs baseline: 1.2061x; 1.0957x over previous
//
#include <hip/hip_runtime.h>

// Problem constants (from reference setup_inputs)
constexpr int B = 16;
constexpr int D = 256;
constexpr int K = 18;
constexpr int SZ = 128;
constexpr int S = SZ * SZ;      // 16384 positions per plane
constexpr int N = S / 2;        // 8192 sampled positions

// ---------------------------------------------------------------------------
// Prep (parallel): blocks 0..31 scatter mask ones (mask pre-zeroed by memset);
// blocks 32..103 compute p2[b*K+k] = ||proto||^2 in fp64, one row per warp.
// (identical to the passing round-5 version)
// ---------------------------------------------------------------------------
__global__ __launch_bounds__(256) void prep2_kernel(
    const float* __restrict__ proto,
    const int* __restrict__ idx,
    unsigned char* __restrict__ mask,
    double* __restrict__ p2) {
  const int blk = blockIdx.x;
  if (blk < 32) {
    mask[idx[blk * 256 + threadIdx.x]] = 1;   // indices are a permutation: no conflicts
  } else {
    const int row  = (blk - 32) * 4 + (threadIdx.x >> 6);  // 0..287 = b*K+k
    const int lane = threadIdx.x & 63;
    const float4 v = *(const float4*)(proto + (size_t)row * D + lane * 4);
    double s = (double)v.x * (double)v.x + (double)v.y * (double)v.y
             + (double)v.z * (double)v.z + (double)v.w * (double)v.w;
#pragma unroll
    for (int off = 1; off < 64; off <<= 1)
      s += __shfl_xor(s, off, 64);
    if (lane == 0) p2[row] = s;
  }
}

// ---------------------------------------------------------------------------
// Phase 2 (dense, coalesced, P=4 positions/thread): block = (b, 1024-pos
// chunk), 256 threads. Thread owns positions s0, s0+1, s0+512, s0+513
// (two float2 loads per d). Each LDS proto broadcast (ds_read_b64) now
// feeds 4 FMAs -> DS cycles/CU halve vs round 5 (the measured 90 us was
// DS-issue bound: 18 reads/d/wave * 6 cyc).
// Register budget: acc 4x18 fp64 = 72 VGPR + ~40 overhead. waves_per_eu(1,2)
// removes the compiler's spill-for-occupancy incentive (round 7/8 failure:
// VGPR_Count 128/48 < live state -> silent scratch spill in L2).
// fp64 acc, d-order 0..255 ascending per position -> argmin decisions
// identical to rounds 1-5 (absmax 0.0 each time).
// ---------------------------------------------------------------------------
__global__ __launch_bounds__(256)
__attribute__((amdgpu_waves_per_eu(1, 2)))
void argmin_kernel(
    const float* __restrict__ assp,
    const float* __restrict__ proto,
    const double* __restrict__ p2,
    signed char* __restrict__ table) {
  __shared__ double spd[D][K];    // 36 KiB

  const int b     = blockIdx.x & 15;   // batches spread across XCDs
  const int chunk = blockIdx.x >> 4;   // 0..15

  const float* pb = proto + (size_t)b * K * D;
  for (int i = threadIdx.x; i < K * D; i += 256)
    spd[i & 255][i >> 8] = (double)pb[i];
  __syncthreads();

  const int s0 = chunk * 1024 + 2 * threadIdx.x;     // pos s0,s0+1,s0+512,s0+513
  const float* fA = assp + (size_t)b * D * S + s0;

  double acc[4][K];
#pragma unroll
  for (int jp = 0; jp < 4; ++jp)
#pragma unroll
    for (int k = 0; k < K; ++k) acc[jp][k] = 0.0;

  for (int d0 = 0; d0 < D; d0 += 8) {
    float2 fv[8][2];
#pragma unroll
    for (int jd = 0; jd < 8; ++jd) {                 // 16 coalesced loads in flight
      fv[jd][0] = *(const float2*)(fA + (size_t)(d0 + jd) * S);
      fv[jd][1] = *(const float2*)(fA + (size_t)(d0 + jd) * S + 512);
    }
#pragma unroll
    for (int jd = 0; jd < 8; ++jd) {
      const double f0 = (double)fv[jd][0].x;
      const double f1 = (double)fv[jd][0].y;
      const double f2 = (double)fv[jd][1].x;
      const double f3 = (double)fv[jd][1].y;
      const double* pr = spd[d0 + jd];               // wave-uniform -> LDS broadcast
#pragma unroll
      for (int k = 0; k < K; ++k) {
        const double pk = pr[k];
        acc[0][k] += f0 * pk;
        acc[1][k] += f1 * pk;
        acc[2][k] += f2 * pk;
        acc[3][k] += f3 * pk;
      }
    }
  }

  // ---- per-position argmin (strict <, ascending k = numpy first-min) ----
  const double* p2b = p2 + (size_t)b * K;
  double best[4];
  int kst[4];
#pragma unroll
  for (int jp = 0; jp < 4; ++jp) { best[jp] = 1e300; kst[jp] = 0; }
#pragma unroll
  for (int k = 0; k < K; ++k) {
    const double pk2 = p2b[k];
#pragma unroll
    for (int jp = 0; jp < 4; ++jp) {
      const double d2 = pk2 - 2.0 * acc[jp][k];
      if (d2 < best[jp]) { best[jp] = d2; kst[jp] = k; }
    }
  }

  signed char* tb = table + (size_t)b * S + s0;
  tb[0]   = (signed char)kst[0];
  tb[1]   = (signed char)kst[1];
  tb[512] = (signed char)kst[2];
  tb[513] = (signed char)kst[3];
}

// ---------------------------------------------------------------------------
// Phase 3 (identical to passing round 5): one block per (b,d) plane, walked
// d-DESCENDING (reverse of argmin's read-time order -> L3 tail reuse).
// Plain stores only: nontemporal stores broke post-timing validation (r4).
// ---------------------------------------------------------------------------
__global__ __launch_bounds__(256) void scatter_kernel(
    const float* __restrict__ assp,
    const float* __restrict__ proto,
    const signed char* __restrict__ table,
    const unsigned char* __restrict__ mask,
    float* __restrict__ out) {
  const int d  = 255 - (blockIdx.x >> 4);   // d descending across all b together
  const int b  = blockIdx.x & 15;
  const int bd = b * D + d;

  __shared__ float sp[K];
  if (threadIdx.x < K)
    sp[threadIdx.x] = proto[((size_t)b * K + threadIdx.x) * D + d];
  __syncthreads();

  const signed char* tb = table + (size_t)b * S;
  const float4* in4 = (const float4*)(assp + (size_t)bd * S);
  float4* out4 = (float4*)(out + (size_t)bd * S);

#pragma unroll
  for (int it = 0; it < S / 4 / 256; ++it) {   // 16 iterations
    const int i = it * 256 + threadIdx.x;      // float4 index within plane
    char4 t, m;
    *(int*)&t = ((const int*)tb)[i];
    *(int*)&m = ((const int*)mask)[i];
    float4 v = in4[i];
    if (m.x) v.x = sp[(int)t.x];
    if (m.y) v.y = sp[(int)t.y];
    if (m.z) v.z = sp[(int)t.z];
    if (m.w) v.w = sp[(int)t.w];
    out4[i] = v;
  }
}

extern "C" void kernel_launch(void* const* d_in, const int* in_sizes, int n_in,
                              void* d_out, int out_size, void* d_ws, size_t ws_size,
                              hipStream_t stream) {
  const float* assp  = (const float*)d_in[0];
  const float* proto = (const float*)d_in[1];
  const int*   idx   = (const int*)d_in[2];
  float* out = (float*)d_out;

  // ws layout: [table: B*S bytes][mask: S bytes][p2: B*K doubles]
  signed char*   table = (signed char*)d_ws;
  unsigned char* mask  = (unsigned char*)d_ws + (size_t)B * S;
  double*        p2    = (double*)((char*)d_ws + (size_t)B * S + S);

  hipMemsetAsync(mask, 0, S, stream);   // 16 KiB
  prep2_kernel<<<104, 256, 0, stream>>>(proto, idx, mask, p2);
  argmin_kernel<<<B * (S / 1024), 256, 0, stream>>>(assp, proto, p2, table);
  scatter_kernel<<<B * D, 256, 0, stream>>>(assp, proto, table, mask, out);
}